// Round 1
// baseline (260.635 us; speedup 1.0000x reference)
//
#include <hip/hip_runtime.h>
#include <stdint.h>

// Q4_0 dequant-GEMM: y[t,o] = sum_k x[t,k] * s[o,k/32]*(q[o,k]-8) + bias[o]
// M=16 tokens, K=4096, N=11008. HBM-bound on the 180 MB int32 qweight read.
// Strategy: mfma_f32_16x16x32_bf16 (M=16 exact), dequant-on-the-fly into the
// B fragment; x pre-packed once into A-fragment bf16 layout in d_ws (128 KB).
// K split x4 across blocks (2752 blocks -> 10.75/CU, ~2% tail) and x4 waves
// within a block; LDS combine + one fp32 atomicAdd per output per block.

typedef __attribute__((ext_vector_type(8))) short bf16x8;  // 8 bf16 (4 VGPRs)
typedef __attribute__((ext_vector_type(4))) float f32x4;   // mfma accumulator

#define OUT_F 11008
#define IN_F  4096
#define NB    128   // quant blocks along K (32 elements each)

// ---------------------------------------------------------------------------
// Kernel 1: zero d_out (176128 f32 = 44032 float4) AND pack x into A-fragment
// bf16 layout in ws: for kb in [0,128): 64 lanes x 16B; lane l holds
// x[t=l&15][kb*32 + (l>>4)*8 + j], j=0..7, as bf16 (round-half-up).
// ---------------------------------------------------------------------------
__global__ __launch_bounds__(256) void prep_kernel(const float* __restrict__ x,
                                                   float* __restrict__ out,
                                                   uint32_t* __restrict__ wsA) {
  int tid = blockIdx.x * 256 + threadIdx.x;
  if (tid < 44032) {
    f32x4 z = {0.f, 0.f, 0.f, 0.f};
    ((f32x4*)out)[tid] = z;
  }
  if (tid < 8192) {
    int kb = tid >> 6;
    int l  = tid & 63;
    int t  = l & 15;
    int k  = kb * 32 + (l >> 4) * 8;
    const float* xp = x + t * IN_F + k;
    uint32_t u[8];
#pragma unroll
    for (int j = 0; j < 8; ++j) {
      union { float f; uint32_t i; } c;
      c.f  = xp[j];
      u[j] = c.i + 0x8000u;  // round-half-up to bf16
    }
    uint4 p;
    p.x = (u[1] & 0xFFFF0000u) | (u[0] >> 16);
    p.y = (u[3] & 0xFFFF0000u) | (u[2] >> 16);
    p.z = (u[5] & 0xFFFF0000u) | (u[4] >> 16);
    p.w = (u[7] & 0xFFFF0000u) | (u[6] >> 16);
    *(uint4*)(wsA + kb * 256 + l * 4) = p;
  }
}

// ---------------------------------------------------------------------------
// Kernel 2: main MFMA GEMM. bid -> (tile = bid>>2, kq = bid&3). Each block:
// 16 outputs (ob..ob+15), K-quarter kq*1024..+1023, 4 waves x 8 k-blocks.
// ---------------------------------------------------------------------------
__global__ __launch_bounds__(256) void qgemm_kernel(const int* __restrict__ qw,
                                                    const float* __restrict__ scales,
                                                    const float* __restrict__ bias,
                                                    const uint32_t* __restrict__ wsA,
                                                    float* __restrict__ out) {
  const int bid  = blockIdx.x;
  const int kq   = bid & 3;
  const int ob   = (bid >> 2) << 4;
  const int tid  = threadIdx.x;
  const int wave = tid >> 6;
  const int lane = tid & 63;
  const int col  = lane & 15;   // output-column / A-row selector
  const int kr   = lane >> 4;   // k sub-chunk 0..3

  const int kb0 = kq * 32 + wave * 8;  // first quant-block index for this wave

  const int*      qbase = qw + (ob + col) * IN_F + kr * 8;  // B rows, 32B/lane
  const float*    sbase = scales + (ob + col) * NB;
  const uint32_t* abase = wsA + lane * 4;

  f32x4 acc = {0.f, 0.f, 0.f, 0.f};

#pragma unroll
  for (int i = 0; i < 8; ++i) {
    const int kb = kb0 + i;
    // A fragment: 16B of pre-packed bf16 x (L2-hot)
    uint4 a = *(const uint4*)(abase + kb * 256);
    // B: 8 int32 quants from this lane's output row (coalesced 128B/row)
    const int* qp = qbase + kb * 32;
    int4 q0 = *(const int4*)(qp);
    int4 q1 = *(const int4*)(qp + 4);
    float s   = sbase[kb];
    float m8s = -8.f * s;
    // dequant: w = s*q - 8s, then truncate-pack to bf16 pairs
    float w0 = fmaf((float)q0.x, s, m8s);
    float w1 = fmaf((float)q0.y, s, m8s);
    float w2 = fmaf((float)q0.z, s, m8s);
    float w3 = fmaf((float)q0.w, s, m8s);
    float w4 = fmaf((float)q1.x, s, m8s);
    float w5 = fmaf((float)q1.y, s, m8s);
    float w6 = fmaf((float)q1.z, s, m8s);
    float w7 = fmaf((float)q1.w, s, m8s);
    union { uint32_t u[4]; bf16x8 v; } A, B;
    A.u[0] = a.x; A.u[1] = a.y; A.u[2] = a.z; A.u[3] = a.w;
    B.u[0] = (__float_as_uint(w1) & 0xFFFF0000u) | (__float_as_uint(w0) >> 16);
    B.u[1] = (__float_as_uint(w3) & 0xFFFF0000u) | (__float_as_uint(w2) >> 16);
    B.u[2] = (__float_as_uint(w5) & 0xFFFF0000u) | (__float_as_uint(w4) >> 16);
    B.u[3] = (__float_as_uint(w7) & 0xFFFF0000u) | (__float_as_uint(w6) >> 16);
    acc = __builtin_amdgcn_mfma_f32_16x16x32_bf16(A.v, B.v, acc, 0, 0, 0);
  }

  // Cross-wave combine. C/D layout: lane holds D[row=kr*4+r][col], col=lane&15.
  __shared__ float red[4][256];
#pragma unroll
  for (int r = 0; r < 4; ++r) {
    int t = kr * 4 + r;
    red[wave][t * 16 + col] = acc[r];
  }
  __syncthreads();

  float v = red[0][tid] + red[1][tid] + red[2][tid] + red[3][tid];
  int t = tid >> 4;
  int o = ob + (tid & 15);
  if (kq == 0) v += bias[o];
  __hip_atomic_fetch_add(out + t * OUT_F + o, v, __ATOMIC_RELAXED,
                         __HIP_MEMORY_SCOPE_AGENT);
}

// ---------------------------------------------------------------------------
extern "C" void kernel_launch(void* const* d_in, const int* in_sizes, int n_in,
                              void* d_out, int out_size, void* d_ws, size_t ws_size,
                              hipStream_t stream) {
  const float* x      = (const float*)d_in[0];
  const int*   qw     = (const int*)d_in[1];
  const float* scales = (const float*)d_in[2];
  const float* bias   = (const float*)d_in[3];
  float*    out = (float*)d_out;
  uint32_t* wsA = (uint32_t*)d_ws;  // needs 128 KiB scratch

  // 172*256 = 44032 threads: covers out-zeroing (44032 f4) and x-pack (8192)
  prep_kernel<<<172, 256, 0, stream>>>(x, out, wsA);
  // 688 output tiles x 4 K-quarters
  qgemm_kernel<<<2752, 256, 0, stream>>>(qw, scales, bias, wsA, out);
}

// Round 2
// 256.359 us; speedup vs baseline: 1.0167x; 1.0167x over previous
//
#include <hip/hip_runtime.h>
#include <stdint.h>

// Q4_0 dequant-GEMM: y[t,o] = sum_k x[t,k] * s[o,k/32]*(q[o,k]-8) + bias[o]
// M=16 tokens, K=4096, N=11008. HBM-bound on the 172 MiB int32 qweight read
// (floor ~27 us at 6.3 TB/s). mfma_f32_16x16x32_bf16 (M=16 exact, K=32 = one
// quant block); dequant-on-the-fly into B fragment; x pre-packed once into
// A-fragment bf16 layout in d_ws (128 KB, L2-hot). K split x4 across blocks
// (2752 blocks -> 10.75/CU, ~2% tail), x4 waves within a block; LDS combine +
// one fp32 atomicAdd per output per block.
//
// R2 changes vs R1: per-lane scales preloaded (2x float4, removes 8 in-loop
// gathers); qweight loads nontemporal (nt - no L2 pollution, protects hot wsA);
// bf16 pack via single v_perm_b32 instead of and/shr/or.

typedef __attribute__((ext_vector_type(8))) short bf16x8;  // 8 bf16 (4 VGPRs)
typedef __attribute__((ext_vector_type(4))) float f32x4;   // mfma accumulator
typedef __attribute__((ext_vector_type(4))) int   i32x4;

#define OUT_F 11008
#define IN_F  4096
#define NB    128   // quant blocks along K (32 elements each)

// ---------------------------------------------------------------------------
// Kernel 1: zero d_out (176128 f32 = 44032 float4) AND pack x into A-fragment
// bf16 layout in ws: for kb in [0,128): 64 lanes x 16B; lane l holds
// x[t=l&15][kb*32 + (l>>4)*8 + j], j=0..7, as bf16 (round-half-up).
// ---------------------------------------------------------------------------
__global__ __launch_bounds__(256) void prep_kernel(const float* __restrict__ x,
                                                   float* __restrict__ out,
                                                   uint32_t* __restrict__ wsA) {
  int tid = blockIdx.x * 256 + threadIdx.x;
  if (tid < 44032) {
    f32x4 z = {0.f, 0.f, 0.f, 0.f};
    ((f32x4*)out)[tid] = z;
  }
  if (tid < 8192) {
    int kb = tid >> 6;
    int l  = tid & 63;
    int t  = l & 15;
    int k  = kb * 32 + (l >> 4) * 8;
    const float* xp = x + t * IN_F + k;
    uint32_t u[8];
#pragma unroll
    for (int j = 0; j < 8; ++j) {
      union { float f; uint32_t i; } c;
      c.f  = xp[j];
      u[j] = c.i + 0x8000u;  // round-half-up to bf16
    }
    uint4 p;
    p.x = (u[1] & 0xFFFF0000u) | (u[0] >> 16);
    p.y = (u[3] & 0xFFFF0000u) | (u[2] >> 16);
    p.z = (u[5] & 0xFFFF0000u) | (u[4] >> 16);
    p.w = (u[7] & 0xFFFF0000u) | (u[6] >> 16);
    *(uint4*)(wsA + kb * 256 + l * 4) = p;
  }
}

// ---------------------------------------------------------------------------
// Kernel 2: main MFMA GEMM. bid -> (tile = bid>>2, kq = bid&3). Each block:
// 16 outputs (ob..ob+15), K-quarter kq*1024..+1023, 4 waves x 8 k-blocks.
// ---------------------------------------------------------------------------
__global__ __launch_bounds__(256) void qgemm_kernel(const int* __restrict__ qw,
                                                    const float* __restrict__ scales,
                                                    const float* __restrict__ bias,
                                                    const uint32_t* __restrict__ wsA,
                                                    float* __restrict__ out) {
  const int bid  = blockIdx.x;
  const int kq   = bid & 3;
  const int ob   = (bid >> 2) << 4;
  const int tid  = threadIdx.x;
  const int wave = tid >> 6;
  const int lane = tid & 63;
  const int col  = lane & 15;   // output-row selector (B fragment row)
  const int kr   = lane >> 4;   // k sub-chunk 0..3

  const int kb0 = kq * 32 + wave * 8;  // first quant-block index for this wave

  // per-lane qweight base: row (ob+col), starting at this wave's k range
  const int* qbase = qw + (size_t)(ob + col) * IN_F + kb0 * 32 + kr * 8;
  const uint32_t* abase = wsA + kb0 * 256 + lane * 4;

  // preload this lane's 8 scales (32B, aligned: kb0 is a multiple of 8)
  const float* sp = scales + (ob + col) * NB + kb0;
  f32x4 sA = *(const f32x4*)sp;
  f32x4 sB = *(const f32x4*)(sp + 4);

  f32x4 acc = {0.f, 0.f, 0.f, 0.f};

#pragma unroll
  for (int i = 0; i < 8; ++i) {
    // A fragment: 16B of pre-packed bf16 x (L2-hot)
    uint4 a = *(const uint4*)(abase + i * 256);
    // B: 8 int32 quants from this lane's output row (nontemporal: streamed
    // once, keep out of L2 so wsA stays resident)
    const i32x4* qp = (const i32x4*)(qbase + i * 32);
    i32x4 q0 = __builtin_nontemporal_load(qp);
    i32x4 q1 = __builtin_nontemporal_load(qp + 1);
    float s   = (i < 4) ? sA[i] : sB[i - 4];
    float m8s = -8.f * s;
    // dequant: w = s*q - 8s  (q-8 exact in fp32; fma then truncate to bf16)
    uint32_t w0 = __float_as_uint(fmaf((float)q0.x, s, m8s));
    uint32_t w1 = __float_as_uint(fmaf((float)q0.y, s, m8s));
    uint32_t w2 = __float_as_uint(fmaf((float)q0.z, s, m8s));
    uint32_t w3 = __float_as_uint(fmaf((float)q0.w, s, m8s));
    uint32_t w4 = __float_as_uint(fmaf((float)q1.x, s, m8s));
    uint32_t w5 = __float_as_uint(fmaf((float)q1.y, s, m8s));
    uint32_t w6 = __float_as_uint(fmaf((float)q1.z, s, m8s));
    uint32_t w7 = __float_as_uint(fmaf((float)q1.w, s, m8s));
    union { uint32_t u[4]; bf16x8 v; } A, B;
    A.u[0] = a.x; A.u[1] = a.y; A.u[2] = a.z; A.u[3] = a.w;
    // single v_perm_b32 packs two bf16 (truncate) per dword
    B.u[0] = __builtin_amdgcn_perm(w1, w0, 0x07060302u);
    B.u[1] = __builtin_amdgcn_perm(w3, w2, 0x07060302u);
    B.u[2] = __builtin_amdgcn_perm(w5, w4, 0x07060302u);
    B.u[3] = __builtin_amdgcn_perm(w7, w6, 0x07060302u);
    acc = __builtin_amdgcn_mfma_f32_16x16x32_bf16(A.v, B.v, acc, 0, 0, 0);
  }

  // Cross-wave combine. C/D layout: lane holds D[row=kr*4+r][col], col=lane&15.
  __shared__ float red[4][256];
#pragma unroll
  for (int r = 0; r < 4; ++r) {
    int t = kr * 4 + r;
    red[wave][t * 16 + col] = acc[r];
  }
  __syncthreads();

  float v = red[0][tid] + red[1][tid] + red[2][tid] + red[3][tid];
  int t = tid >> 4;
  int o = ob + (tid & 15);
  if (kq == 0) v += bias[o];
  __hip_atomic_fetch_add(out + t * OUT_F + o, v, __ATOMIC_RELAXED,
                         __HIP_MEMORY_SCOPE_AGENT);
}

// ---------------------------------------------------------------------------
extern "C" void kernel_launch(void* const* d_in, const int* in_sizes, int n_in,
                              void* d_out, int out_size, void* d_ws, size_t ws_size,
                              hipStream_t stream) {
  const float* x      = (const float*)d_in[0];
  const int*   qw     = (const int*)d_in[1];
  const float* scales = (const float*)d_in[2];
  const float* bias   = (const float*)d_in[3];
  float*    out = (float*)d_out;
  uint32_t* wsA = (uint32_t*)d_ws;  // needs 128 KiB scratch

  // 172*256 = 44032 threads: covers out-zeroing (44032 f4) and x-pack (8192)
  prep_kernel<<<172, 256, 0, stream>>>(x, out, wsA);
  // 688 output tiles x 4 K-quarters
  qgemm_kernel<<<2752, 256, 0, stream>>>(qw, scales, bias, wsA, out);
}